// Round 1
// baseline (11579.031 us; speedup 1.0000x reference)
//
#include <hip/hip_runtime.h>
#include <cstdint>

// Problem constants
#define Bsz 2048
#define Ssz 50
#define Esz 256
#define Hsz 512
#define Wsz 256
#define Lsz 50
#define Vsz 51

// JAX RNG semantics: 1 = threefry_partitionable (jax >= 0.4.36 default), 0 = original
#define JAX_THREEFRY_PARTITIONABLE 1

// ---------------- threefry2x32 (20 rounds), key words (k0,k1) ----------------
__host__ __device__ __forceinline__ void threefry2x32_hd(
    unsigned k0, unsigned k1, unsigned x0, unsigned x1,
    unsigned& o0, unsigned& o1) {
  unsigned ks2 = k0 ^ k1 ^ 0x1BD11BDAu;
  x0 += k0; x1 += k1;
#define TF_RND(r) { x0 += x1; x1 = (x1 << (r)) | (x1 >> (32 - (r))); x1 ^= x0; }
  TF_RND(13) TF_RND(15) TF_RND(26) TF_RND(6)
  x0 += k1; x1 += ks2 + 1u;
  TF_RND(17) TF_RND(29) TF_RND(16) TF_RND(24)
  x0 += ks2; x1 += k0 + 2u;
  TF_RND(13) TF_RND(15) TF_RND(26) TF_RND(6)
  x0 += k0; x1 += k1 + 3u;
  TF_RND(17) TF_RND(29) TF_RND(16) TF_RND(24)
  x0 += k1; x1 += ks2 + 4u;
  TF_RND(13) TF_RND(15) TF_RND(26) TF_RND(6)
  x0 += ks2; x1 += k0 + 5u;
#undef TF_RND
  o0 = x0; o1 = x1;
}

// ---------------- prep: Wpack[j][k][g] = Whh[g*512+j][k] ----------------
__global__ __launch_bounds__(256) void prep_pack(const float* __restrict__ src,
                                                 float* __restrict__ dst) {
  int idx = blockIdx.x * 256 + threadIdx.x;   // < 512*512
  int j = idx >> 9, k = idx & 511;
  float4 v;
  v.x = src[(size_t)(0 * 512 + j) * 512 + k];
  v.y = src[(size_t)(1 * 512 + j) * 512 + k];
  v.z = src[(size_t)(2 * 512 + j) * 512 + k];
  v.w = src[(size_t)(3 * 512 + j) * 512 + k];
  ((float4*)dst)[idx] = v;
}

// ---------------- prep: encInP[v][j][g] = emb[v].Wih[g*512+j] + bih + bhh ----
__global__ __launch_bounds__(256) void prep_encin(
    const float* __restrict__ emb, const float* __restrict__ Wih,
    const float* __restrict__ bih, const float* __restrict__ bhh,
    float* __restrict__ encInP) {
  int wid = blockIdx.x * 4 + (threadIdx.x >> 6);
  int lane = threadIdx.x & 63;
  if (wid >= Vsz * 2048) return;
  int v = wid >> 11, col = wid & 2047;
  float4 e = ((const float4*)emb)[v * 64 + lane];
  float4 w = ((const float4*)Wih)[col * 64 + lane];
  float d = e.x * w.x + e.y * w.y + e.z * w.z + e.w * w.w;
  for (int off = 32; off; off >>= 1) d += __shfl_xor(d, off);
  if (lane == 0) {
    int g = col >> 9, j = col & 511;
    encInP[(size_t)v * 2048 + j * 4 + g] = d + bih[col] + bhh[col];
  }
}

// ---------------- prep: dbiasP[j][g] = dec_bih + dec_bhh ----------------
__global__ __launch_bounds__(256) void prep_dbias(const float* __restrict__ a,
                                                  const float* __restrict__ b,
                                                  float* __restrict__ dst) {
  int col = blockIdx.x * 256 + threadIdx.x;  // < 2048
  int g = col >> 9, j = col & 511;
  dst[j * 4 + g] = a[col] + b[col];
}

// ---------------- fused gates GEMM + LSTM cell ----------------
// C4[b][j] = sum_k hin[b][k] * Wpack[j][k][0..3]; tile 64b x 32j, KT=32.
// epilogue: gates(+encIn[tok] or dbias) -> sigmoid/tanh -> c,h
__global__ __launch_bounds__(256) void gates_step(
    const float* __restrict__ hin, const float* __restrict__ Wpack,
    const float* __restrict__ addtab, const int* __restrict__ input, int tstep,
    float* __restrict__ hout, float* __restrict__ cio) {
  __shared__ float hsT[32][68];     // [kk][b], +4 pad
  __shared__ float4 WsT[32][33];    // [kk][j], +1 pad
  const int t = threadIdx.x;
  const int tj = t & 15, tb = t >> 4;
  const int bBase = (blockIdx.x >> 4) * 64;   // 32 b-tiles
  const int jBase = (blockIdx.x & 15) * 32;   // 16 j-tiles

  float4 acc[4][2];
#pragma unroll
  for (int i = 0; i < 4; ++i)
#pragma unroll
    for (int p = 0; p < 2; ++p) acc[i][p] = make_float4(0.f, 0.f, 0.f, 0.f);

  const int lrow = t >> 3;   // 0..31
  const int lc4 = t & 7;     // 0..7
  const int wk = t & 31;     // 0..31
  const int wj = t >> 5;     // 0..7

  for (int k0 = 0; k0 < Hsz; k0 += 32) {
    // stage h tile (64 rows x 32 cols), transposed into hsT[k][b]
    {
      float4 v = *((const float4*)(hin + (size_t)(bBase + lrow) * Hsz + k0) + lc4);
      hsT[lc4 * 4 + 0][lrow] = v.x; hsT[lc4 * 4 + 1][lrow] = v.y;
      hsT[lc4 * 4 + 2][lrow] = v.z; hsT[lc4 * 4 + 3][lrow] = v.w;
      float4 v2 = *((const float4*)(hin + (size_t)(bBase + lrow + 32) * Hsz + k0) + lc4);
      hsT[lc4 * 4 + 0][lrow + 32] = v2.x; hsT[lc4 * 4 + 1][lrow + 32] = v2.y;
      hsT[lc4 * 4 + 2][lrow + 32] = v2.z; hsT[lc4 * 4 + 3][lrow + 32] = v2.w;
    }
    // stage W tile: 32 j-rows x 32 k-cols of float4 -> WsT[k][j]
#pragma unroll
    for (int i = 0; i < 4; ++i) {
      int j = wj + 8 * i;
      WsT[wk][j] = *((const float4*)Wpack + (size_t)(jBase + j) * Hsz + k0 + wk);
    }
    __syncthreads();
#pragma unroll 8
    for (int kk = 0; kk < 32; ++kk) {
      float4 hv = *(const float4*)&hsT[kk][tb * 4];
      float4 w0 = WsT[kk][tj * 2];
      float4 w1 = WsT[kk][tj * 2 + 1];
#define FMA4(A, s, Wv)                       \
  A.x = fmaf(s, Wv.x, A.x); A.y = fmaf(s, Wv.y, A.y); \
  A.z = fmaf(s, Wv.z, A.z); A.w = fmaf(s, Wv.w, A.w);
      FMA4(acc[0][0], hv.x, w0) FMA4(acc[0][1], hv.x, w1)
      FMA4(acc[1][0], hv.y, w0) FMA4(acc[1][1], hv.y, w1)
      FMA4(acc[2][0], hv.z, w0) FMA4(acc[2][1], hv.z, w1)
      FMA4(acc[3][0], hv.w, w0) FMA4(acc[3][1], hv.w, w1)
#undef FMA4
    }
    __syncthreads();
  }

#pragma unroll
  for (int i = 0; i < 4; ++i) {
    const int b = bBase + tb * 4 + i;
    const float4* arow =
        (const float4*)(input ? (addtab + (size_t)input[(size_t)b * Ssz + tstep] * 2048)
                              : addtab);
#pragma unroll
    for (int p = 0; p < 2; ++p) {
      const int j = jBase + tj * 2 + p;
      float4 a = acc[i][p];
      float4 av = arow[j];
      float gi = a.x + av.x;
      float gf = a.y + av.y;
      float gg = a.z + av.z;
      float go = a.w + av.w;
      float si = 1.0f / (1.0f + expf(-gi));
      float sf = 1.0f / (1.0f + expf(-gf));
      float sg = tanhf(gg);
      float so = 1.0f / (1.0f + expf(-go));
      size_t oo = (size_t)b * Hsz + j;
      float cn = sf * cio[oo] + si * sg;
      cio[oo] = cn;
      hout[oo] = so * tanhf(cn);
    }
  }
}

// ---------------- blend GEMM: out[b][w] = sum_k h[b][k]*Wm[w][k] ----------------
// tile 32b x 64w, KT=32; out row stride parameterized (blend1 rows / blend2)
__global__ __launch_bounds__(256) void blend_gemm(
    const float* __restrict__ hin, const float* __restrict__ Wm,
    float* __restrict__ out, int rowStride) {
  __shared__ float hsT[32][36];   // [kk][b(32)]
  __shared__ float WsT[32][68];   // [kk][w(64)]
  const int t = threadIdx.x;
  const int tw = t & 15, tb = t >> 4;
  const int bBase = (blockIdx.x >> 2) * 32;   // 64 b-tiles
  const int wBase = (blockIdx.x & 3) * 64;    // 4 w-tiles
  float4 acc[2];
  acc[0] = make_float4(0.f, 0.f, 0.f, 0.f);
  acc[1] = make_float4(0.f, 0.f, 0.f, 0.f);
  const int lrow = t >> 3, lc4 = t & 7;
  for (int k0 = 0; k0 < Hsz; k0 += 32) {
    {
      float4 v = *((const float4*)(hin + (size_t)(bBase + lrow) * Hsz + k0) + lc4);
      hsT[lc4 * 4 + 0][lrow] = v.x; hsT[lc4 * 4 + 1][lrow] = v.y;
      hsT[lc4 * 4 + 2][lrow] = v.z; hsT[lc4 * 4 + 3][lrow] = v.w;
    }
    {
      float4 v = *((const float4*)(Wm + (size_t)(wBase + lrow) * Hsz + k0) + lc4);
      WsT[lc4 * 4 + 0][lrow] = v.x; WsT[lc4 * 4 + 1][lrow] = v.y;
      WsT[lc4 * 4 + 2][lrow] = v.z; WsT[lc4 * 4 + 3][lrow] = v.w;
      float4 v2 = *((const float4*)(Wm + (size_t)(wBase + lrow + 32) * Hsz + k0) + lc4);
      WsT[lc4 * 4 + 0][lrow + 32] = v2.x; WsT[lc4 * 4 + 1][lrow + 32] = v2.y;
      WsT[lc4 * 4 + 2][lrow + 32] = v2.z; WsT[lc4 * 4 + 3][lrow + 32] = v2.w;
    }
    __syncthreads();
#pragma unroll 8
    for (int kk = 0; kk < 32; ++kk) {
      float2 hv = *(const float2*)&hsT[kk][tb * 2];
      float4 wv = *(const float4*)&WsT[kk][tw * 4];
      acc[0].x = fmaf(hv.x, wv.x, acc[0].x); acc[0].y = fmaf(hv.x, wv.y, acc[0].y);
      acc[0].z = fmaf(hv.x, wv.z, acc[0].z); acc[0].w = fmaf(hv.x, wv.w, acc[0].w);
      acc[1].x = fmaf(hv.y, wv.x, acc[1].x); acc[1].y = fmaf(hv.y, wv.y, acc[1].y);
      acc[1].z = fmaf(hv.y, wv.z, acc[1].z); acc[1].w = fmaf(hv.y, wv.w, acc[1].w);
    }
    __syncthreads();
  }
#pragma unroll
  for (int i = 0; i < 2; ++i) {
    const int b = bBase + tb * 2 + i;
    *((float4*)(out + (size_t)b * rowStride + wBase) + tw) = acc[i];
  }
}

// ---------------- scores + log_softmax + gumbel sample + mask ----------------
__global__ __launch_bounds__(256) void scores_sample(
    const float* __restrict__ b1, const float* __restrict__ b2,
    const float* __restrict__ vt, unsigned long long* __restrict__ mask,
    float* __restrict__ probs, float* __restrict__ tour,
    int stepk, unsigned kA, unsigned kB) {
  __shared__ float b2s[256];
  __shared__ float vts[256];
  __shared__ float sc[52];
  const int t = threadIdx.x, b = blockIdx.x;
  b2s[t] = b2[(size_t)b * Wsz + t];
  vts[t] = vt[t];
  __syncthreads();
  const int wave = t >> 6, lane = t & 63;
  for (int s = wave; s < Ssz; s += 4) {
    const float* row = b1 + ((size_t)b * Ssz + s) * Wsz;
    float v = 0.f;
#pragma unroll
    for (int q = 0; q < 4; ++q) {
      int w = lane + 64 * q;
      v += vts[w] * tanhf(row[w] + b2s[w]);
    }
    for (int off = 32; off; off >>= 1) v += __shfl_xor(v, off);
    if (lane == 0) sc[s] = v;
  }
  __syncthreads();
  if (wave == 0) {
    unsigned long long m = mask[b];
    float x = (lane < Ssz) ? sc[lane] : -INFINITY;
    if (lane < Ssz && ((m >> lane) & 1ull)) x = -100000.0f;
    float mv = x;
    for (int off = 32; off; off >>= 1) mv = fmaxf(mv, __shfl_xor(mv, off));
    float sh = x - mv;
    float e = (lane < Ssz) ? expf(sh) : 0.f;
    float ssum = e;
    for (int off = 32; off; off >>= 1) ssum += __shfl_xor(ssum, off);
    float lg = logf(ssum);
    float logp = sh - lg;
    if (lane < Ssz) probs[(size_t)b * (Lsz * Ssz) + stepk * Ssz + lane] = logp;

    float val = -INFINITY;
    if (lane < Ssz) {
      unsigned j = (unsigned)(b * Ssz + lane);
      unsigned o0, o1, bits;
#if JAX_THREEFRY_PARTITIONABLE
      threefry2x32_hd(kA, kB, 0u, j, o0, o1);
      bits = o0 ^ o1;
#else
      if (j < 51200u) { threefry2x32_hd(kA, kB, j, j + 51200u, o0, o1); bits = o0; }
      else           { threefry2x32_hd(kA, kB, j - 51200u, j, o0, o1); bits = o1; }
#endif
      float f = __uint_as_float((bits >> 9) | 0x3F800000u) - 1.0f;
      float u = fmaxf(1.17549435e-38f, f + 1.17549435e-38f);
      val = logp - logf(-logf(u));
    }
    int idx = lane;
    for (int off = 32; off; off >>= 1) {
      float ov = __shfl_xor(val, off);
      int oi = __shfl_xor(idx, off);
      if (ov > val || (ov == val && oi < idx)) { val = ov; idx = oi; }
    }
    if (lane == 0) {
      tour[(size_t)b * Lsz + stepk] = (float)idx;
      mask[b] = m | (1ull << idx);
    }
  }
}

extern "C" void kernel_launch(void* const* d_in, const int* in_sizes, int n_in,
                              void* d_out, int out_size, void* d_ws, size_t ws_size,
                              hipStream_t stream) {
  (void)in_sizes; (void)n_in; (void)out_size; (void)ws_size;
  const int*   input = (const int*)d_in[0];
  const float* emb   = (const float*)d_in[1];
  const float* eWih  = (const float*)d_in[2];
  const float* eWhh  = (const float*)d_in[3];
  const float* ebih  = (const float*)d_in[4];
  const float* ebhh  = (const float*)d_in[5];
  /* d_in[6] dec_Wih unused: decoder input is always zero */
  const float* dWhh  = (const float*)d_in[7];
  const float* dbih  = (const float*)d_in[8];
  const float* dbhh  = (const float*)d_in[9];
  const float* W1    = (const float*)d_in[10];
  const float* W2    = (const float*)d_in[11];
  const float* vt    = (const float*)d_in[12];
  float* outF = (float*)d_out;

  float* wsf = (float*)d_ws;
  size_t o = 0;
  float* WpackE = wsf + o; o += (size_t)512 * 512 * 4;
  float* WpackD = wsf + o; o += (size_t)512 * 512 * 4;
  float* encInP = wsf + o; o += (size_t)Vsz * 2048;
  float* dbiasP = wsf + o; o += 2048;
  float* hA  = wsf + o; o += (size_t)Bsz * Hsz;
  float* hB  = wsf + o; o += (size_t)Bsz * Hsz;
  float* cE  = wsf + o; o += (size_t)Bsz * Hsz;
  float* hdA = wsf + o; o += (size_t)Bsz * Hsz;
  float* hdB = wsf + o; o += (size_t)Bsz * Hsz;
  float* cD  = wsf + o; o += (size_t)Bsz * Hsz;
  float* b2  = wsf + o; o += (size_t)Bsz * Wsz;
  float* b1  = wsf + o; o += (size_t)Bsz * Ssz * Wsz;
  unsigned long long* maskp = (unsigned long long*)(wsf + o); o += Bsz * 2;

  hipMemsetAsync(hA, 0, (size_t)Bsz * Hsz * 4, stream);
  hipMemsetAsync(cE, 0, (size_t)Bsz * Hsz * 4, stream);
  hipMemsetAsync(hdA, 0, (size_t)Bsz * Hsz * 4, stream);
  hipMemsetAsync(maskp, 0, (size_t)Bsz * 8, stream);

  prep_pack<<<1024, 256, 0, stream>>>(eWhh, WpackE);
  prep_pack<<<1024, 256, 0, stream>>>(dWhh, WpackD);
  prep_encin<<<(Vsz * 2048) / 4, 256, 0, stream>>>(emb, eWih, ebih, ebhh, encInP);
  prep_dbias<<<8, 256, 0, stream>>>(dbih, dbhh, dbiasP);

  // host-side: step keys = jax.random.split(jax.random.key(42), 50)
  unsigned kAh[Lsz], kBh[Lsz];
  for (int k = 0; k < Lsz; ++k) {
#if JAX_THREEFRY_PARTITIONABLE
    threefry2x32_hd(0u, 42u, 0u, (unsigned)k, kAh[k], kBh[k]);
#else
    unsigned a0, a1, c0, c1;
    if (k < 25) {
      threefry2x32_hd(0u, 42u, 2u * k,      2u * k + 50u, a0, a1); kAh[k] = a0;
      threefry2x32_hd(0u, 42u, 2u * k + 1u, 2u * k + 51u, c0, c1); kBh[k] = c0;
    } else {
      threefry2x32_hd(0u, 42u, 2u * k - 50u, 2u * k,      a0, a1); kAh[k] = a1;
      threefry2x32_hd(0u, 42u, 2u * k - 49u, 2u * k + 1u, c0, c1); kBh[k] = c1;
    }
#endif
  }

  // encoder
  float* hr = hA; float* hw = hB;
  for (int t = 0; t < Ssz; ++t) {
    gates_step<<<512, 256, 0, stream>>>(hr, WpackE, encInP, input, t, hw, cE);
    blend_gemm<<<256, 256, 0, stream>>>(hw, W1, b1 + (size_t)t * Wsz, Ssz * Wsz);
    float* tp = hr; hr = hw; hw = tp;
  }
  // decoder init: c0 = last encoder h, h0 = 0 (hdA), mask = 0
  hipMemcpyAsync(cD, hr, (size_t)Bsz * Hsz * 4, hipMemcpyDeviceToDevice, stream);

  float* dr = hdA; float* dw = hdB;
  for (int k = 0; k < Lsz; ++k) {
    gates_step<<<512, 256, 0, stream>>>(dr, WpackD, dbiasP, nullptr, 0, dw, cD);
    blend_gemm<<<256, 256, 0, stream>>>(dw, W2, b2, Wsz);
    scores_sample<<<Bsz, 256, 0, stream>>>(b1, b2, vt, maskp, outF,
                                           outF + (size_t)Bsz * Lsz * Ssz,
                                           k, kAh[k], kBh[k]);
    float* tp = dr; dr = dw; dw = tp;
  }
}